// Round 11
// baseline (4749.530 us; speedup 1.0000x reference)
//
#include <hip/hip_runtime.h>
#include <hip/hip_bf16.h>

// MomentumDecoder: 2-layer LSTM (B=512,H=512), 256 autoregressive steps.
// Round 11: 2 WGs/CU latency hiding, rebuilt on the r6-proven template.
// 512 WGs x 512 thr; 16 tiles x 32 batch rows; WG=(tile, ct:16 cols).
// One gate per wave (g=wv&3, kh=wv>>2) exactly as r6; dedicated gbuf exchange
// (no LDS overlay); agent-scope atomic flag barriers (r6); XCD-local groups.
// LDS 75.9KB/WG + VGPR<=128 via __launch_bounds__(512,4) -> 2 WGs/CU
// guaranteed, so co-resident WGs hide each other's poll/drain stalls.

#define B_ 512
#define H_ 512
#define T_ 256
#define NWG 512
#define NTHR 512

typedef _Float16 half8_t __attribute__((ext_vector_type(8)));
typedef _Float16 half4_t __attribute__((ext_vector_type(4)));
typedef float floatx4 __attribute__((ext_vector_type(4)));
typedef float floatx2 __attribute__((ext_vector_type(2)));

// ---- d_ws layout ----
#define W16_BYTES  (3u * 4u * H_ * H_ * 2u)     // 6 MiB f16 [W_hh0|W_ih1|W_hh1]
#define HBUF_ELEMS (B_ * H_)
#define HBUF_BYTES (HBUF_ELEMS * 2u)
#define H0_OFF   ((size_t)W16_BYTES)
#define H1_OFF   (H0_OFF + 2 * HBUF_BYTES)
#define BAR_OFF  (H1_OFF + 2 * HBUF_BYTES)      // flags[16][32] + rank[8]
#define PART_OFF (BAR_OFF + 8192)               // 16 tiles x 32 rows x 32 ct f32

__device__ __forceinline__ float sigm_(float x) { return 1.0f / (1.0f + __expf(-x)); }
__device__ __forceinline__ float tanh_(float x) { return 1.0f - 2.0f / (1.0f + __expf(2.0f * x)); }

// ---------------- prep kernels (unchanged, proven) ----------------
__global__ void prep_weights(const float* __restrict__ whh0,
                             const float* __restrict__ wih1,
                             const float* __restrict__ whh1,
                             _Float16* __restrict__ w16) {
    const int QM = (4 * H_ * H_) / 4;
    int i = blockIdx.x * blockDim.x + threadIdx.x;
    if (i >= 3 * QM) return;
    const float* src; int base;
    if (i < QM)          { src = whh0; base = 0; }
    else if (i < 2 * QM) { src = wih1; base = QM; }
    else                 { src = whh1; base = 2 * QM; }
    float4 v = ((const float4*)src)[i - base];
    half4_t h;
    h[0] = (_Float16)v.x; h[1] = (_Float16)v.y; h[2] = (_Float16)v.z; h[3] = (_Float16)v.w;
    ((half4_t*)w16)[i] = h;
}

__global__ void prep_state(const float* __restrict__ h_in,
                           _Float16* __restrict__ H0, _Float16* __restrict__ H1) {
    int i = blockIdx.x * blockDim.x + threadIdx.x;
    float4 a = ((const float4*)h_in)[i];
    float4 b = ((const float4*)h_in)[(B_ * H_) / 4 + i];
    half4_t ha, hb;
    ha[0] = (_Float16)a.x; ha[1] = (_Float16)a.y; ha[2] = (_Float16)a.z; ha[3] = (_Float16)a.w;
    hb[0] = (_Float16)b.x; hb[1] = (_Float16)b.y; hb[2] = (_Float16)b.z; hb[3] = (_Float16)b.w;
    ((half4_t*)H0)[i] = ha;
    ((half4_t*)H1)[i] = hb;
}

// ---------------- helpers ----------------
// global->LDS 16B, aux=0x01 (SC0: L1 bypass; served from the XCD's L2)
#define GLL16(gptr, lptr) __builtin_amdgcn_global_load_lds( \
    (const __attribute__((address_space(1))) unsigned int*)(gptr), \
    (__attribute__((address_space(3))) unsigned int*)(lptr), 16, 0, 0x01)

// Stage this wave's 4 rows of a 32x512 f16 tile (pre-swizzled source).
__device__ __forceinline__ void stage32(const char* gsrc, char* lbuf, int wv, int lane) {
#pragma unroll
    for (int i = 0; i < 4; ++i) {
        int row = wv * 4 + i;
        const char* g_ = gsrc + row * 1024 + (((lane ^ (row & 7)) & 63) << 4);
        GLL16(g_, lbuf + row * 1024);
    }
}

__device__ __forceinline__ floatx2 load8_sc0(const float* p) {
    floatx2 v;
    asm volatile("global_load_dwordx2 %0, %1, off sc0" : "=v"(v) : "v"(p) : "memory");
    return v;
}

// ---------------- main persistent kernel ----------------
__launch_bounds__(NTHR, 4)
__global__ void lstm_decode(
    const float* __restrict__ c_in,
    const float* __restrict__ wih0, const float* __restrict__ bih0,
    const float* __restrict__ bhh0,
    const float* __restrict__ bih1, const float* __restrict__ bhh1,
    const float* __restrict__ fcw, const float* __restrict__ fcb,
    const _Float16* __restrict__ w16,
    _Float16* __restrict__ Hs0, _Float16* __restrict__ Hs1,
    int* __restrict__ bar, float* __restrict__ part,
    float* __restrict__ outp)
{
    __shared__ __align__(16) char bufA[32768];   // h1 tile (phase A)
    __shared__ __align__(16) char bufB[32768];   // h0 tile (persists A->B->next A)
    __shared__ float gbuf[4][32][20];            // gate exchange, padded (r6 style)
    __shared__ float xrow[32];
    __shared__ int sh_tl, sh_ct;

    const int tid  = (int)threadIdx.x;
    const int lane = tid & 63;
    const int wv   = tid >> 6;    // 0..7
    const int g    = wv & 3;      // gate (i,f,g,o)  -- one gate per wave (r6)
    const int kh   = wv >> 2;     // K half (256 wide)
    const int cl   = lane & 15;
    const int kg   = lane >> 4;   // 0..3
    const int erow = tid >> 4;    // 0..31 elementwise row
    const int ecol = tid & 15;    // 0..15 elementwise col

    // ---- XCD-local group formation; 512 WGs -> 64 per XCD -> 2 tiles ----
    if (tid == 0) {
        unsigned int xcc;
        asm volatile("s_getreg_b32 %0, hwreg(HW_REG_XCC_ID)" : "=s"(xcc));
        int rank = atomicAdd(&bar[1024 + (int)(xcc & 7u)], 1);
        sh_tl = (int)(xcc & 7u) * 2 + ((rank >> 5) & 1);
        sh_ct = rank & 31;
    }
    __syncthreads();
    const int tl = sh_tl;        // tile 0..15 (rows tl*32 .. tl*32+31)
    const int ct = sh_ct;

    // ---- persistent weight fragments (r6 layout, one gate) ----
    const int n = g * H_ + ct * 16 + cl;
    half8_t wf0[8], wf1[8], wf2[8];
    {
        const _Float16* r0 = w16 + (size_t)n * H_ + kh * 256 + kg * 8;
        const _Float16* r1 = r0 + 4 * H_ * H_;
        const _Float16* r2 = r0 + 8 * H_ * H_;
#pragma unroll
        for (int ksg = 0; ksg < 8; ++ksg) {
            wf0[ksg] = *(const half8_t*)(r0 + ksg * 32);
            wf1[ksg] = *(const half8_t*)(r1 + ksg * 32);
            wf2[ksg] = *(const half8_t*)(r2 + ksg * 32);
        }
    }
    const float b0   = bih0[n] + bhh0[n];
    const float b1   = bih1[n] + bhh1[n];
    const float wx   = wih0[n];
    const float fcb0 = fcb[0];
    const float fcv  = fcw[ct * 16 + ecol];

    // ---- c-state: 1 elem/thread per layer ----
    float c0_, c1_;
    {
        size_t ba = (size_t)(tl * 32 + erow) * H_ + ct * 16 + ecol;
        c0_ = c_in[ba];
        c1_ = c_in[(size_t)B_ * H_ + ba];
    }

    // A-fragment addressing: row = mt*16+cl, k = kh*256 + ksg*32 + kg*8
    const int abase = cl * 1024 + kh * 512 + kg * 16;
    const int axor  = (cl & 7) << 4;

    int* flagg   = bar + tl * 32;
    float* partg = part + tl * 1024;   // [32 rows][32 ct]
    int ep = 0;

    floatx4 accG0[2], accG1[2];

#define PASS(bufc, wf, acc) do {                                              \
    _Pragma("unroll")                                                         \
    for (int ksg = 0; ksg < 8; ++ksg) {                                       \
        _Pragma("unroll")                                                     \
        for (int mt = 0; mt < 2; ++mt) {                                      \
            int a_ = (abase + mt * 16384 + ksg * 64) ^ axor;                  \
            half8_t av_ = *(const half8_t*)((bufc) + a_);                     \
            acc[mt] = __builtin_amdgcn_mfma_f32_16x16x32_f16(av_, (wf)[ksg],  \
                                                             acc[mt], 0, 0, 0); \
        }                                                                     \
    }                                                                         \
} while (0)

// r6-proven barrier: sync (drain own vmcnt) + signal + wave0 poll + sync
#define GBAR() do {                                                           \
    ++ep;                                                                     \
    __syncthreads();                                                          \
    if (wv == 0) {                                                            \
        if (lane == 0)                                                        \
            __hip_atomic_store(&flagg[ct], ep, __ATOMIC_RELAXED,              \
                               __HIP_MEMORY_SCOPE_AGENT);                     \
        for (;;) {                                                            \
            int v_ = __hip_atomic_load(&flagg[lane & 31], __ATOMIC_RELAXED,   \
                                       __HIP_MEMORY_SCOPE_AGENT);             \
            if (__all(v_ >= ep)) break;                                       \
        }                                                                     \
    }                                                                         \
    __syncthreads();                                                          \
} while (0)

    // ---- prologue ----
    if (tid < 32) xrow[tid] = 0.f;
    stage32((const char*)Hs0 + (size_t)tl * 32 * 1024, bufB, wv, lane);

    for (int t = 0; t < T_; ++t) {
        const size_t pcur = (size_t)(t & 1);
        const size_t pnxt = (size_t)((t + 1) & 1);
        _Float16* h0w = Hs0 + pnxt * HBUF_ELEMS;
        _Float16* h1w = Hs1 + pnxt * HBUF_ELEMS;

        // ======== phase A ========
        floatx2 pv;
        if (t > 0) pv = load8_sc0(partg + erow * 32 + (tid & 15) * 2);
        stage32((const char*)Hs1 + pcur * HBUF_BYTES + (size_t)tl * 32 * 1024,
                bufA, wv, lane);
        if (t > 0) {
            asm volatile("s_waitcnt vmcnt(4)" : "+v"(pv) :: "memory");
            float xs = pv[0] + pv[1];
            xs += __shfl_xor(xs, 1); xs += __shfl_xor(xs, 2);
            xs += __shfl_xor(xs, 4); xs += __shfl_xor(xs, 8);
            xs += fcb0;
            if ((tid & 15) == 0) {
                xrow[erow] = xs;
                if (ct == 0) outp[(size_t)(tl * 32 + erow) * T_ + (t - 1)] = xs;
            }
        }
        __syncthreads();   // xrow visible; drains staging (bufA + prologue bufB)

        // acc init (r6 pattern: kh==0 carries bias + x*wx; kh==1 zero)
#pragma unroll
        for (int mt = 0; mt < 2; ++mt) {
            if (kh == 0) {
#pragma unroll
                for (int r = 0; r < 4; ++r) {
                    accG0[mt][r] = __builtin_fmaf(xrow[mt * 16 + kg * 4 + r], wx, b0);
                    accG1[mt][r] = b1;
                }
            } else {
#pragma unroll
                for (int r = 0; r < 4; ++r) { accG0[mt][r] = 0.f; accG1[mt][r] = 0.f; }
            }
        }

        PASS(bufB, wf0, accG0);                   // h0 x W_hh0^T
        asm volatile("s_waitcnt vmcnt(0) lgkmcnt(0)\n\ts_barrier" ::: "memory");
        PASS(bufA, wf2, accG1);                   // h1 x W_hh1^T (partial)

        // gate0 exchange across kh halves (r6 verbatim)
        if (kh == 0) {
#pragma unroll
            for (int mt = 0; mt < 2; ++mt)
#pragma unroll
                for (int r = 0; r < 4; ++r)
                    gbuf[g][mt * 16 + kg * 4 + r][cl] = accG0[mt][r];
        }
        __syncthreads();
        if (kh == 1) {
#pragma unroll
            for (int mt = 0; mt < 2; ++mt)
#pragma unroll
                for (int r = 0; r < 4; ++r)
                    gbuf[g][mt * 16 + kg * 4 + r][cl] += accG0[mt][r];
        }
        __syncthreads();
        // EW layer 0: update c0, store h0_new (plain -> local L2)
        {
            float i_ = gbuf[0][erow][ecol];
            float f_ = gbuf[1][erow][ecol];
            float q_ = gbuf[2][erow][ecol];
            float o_ = gbuf[3][erow][ecol];
            float cc = sigm_(f_) * c0_ + sigm_(i_) * tanh_(q_);
            c0_ = cc;
            float hv = sigm_(o_) * tanh_(cc);
            h0w[(size_t)(tl * 32 + erow) * H_ + ct * 16 + ecol] = (_Float16)hv;
        }
        GBAR();   // barrier A: h0_new visible tile-wide

        // ======== phase B ========
        stage32((const char*)h0w + (size_t)tl * 32 * 1024, bufB, wv, lane);
        asm volatile("s_waitcnt vmcnt(0) lgkmcnt(0)\n\ts_barrier" ::: "memory");
        PASS(bufB, wf1, accG1);                   // G1 += h0_new x W_ih1^T

        if (kh == 0) {
#pragma unroll
            for (int mt = 0; mt < 2; ++mt)
#pragma unroll
                for (int r = 0; r < 4; ++r)
                    gbuf[g][mt * 16 + kg * 4 + r][cl] = accG1[mt][r];
        }
        __syncthreads();
        if (kh == 1) {
#pragma unroll
            for (int mt = 0; mt < 2; ++mt)
#pragma unroll
                for (int r = 0; r < 4; ++r)
                    gbuf[g][mt * 16 + kg * 4 + r][cl] += accG1[mt][r];
        }
        __syncthreads();
        // EW layer 1 + FC partial
        {
            float i_ = gbuf[0][erow][ecol];
            float f_ = gbuf[1][erow][ecol];
            float q_ = gbuf[2][erow][ecol];
            float o_ = gbuf[3][erow][ecol];
            float cc = sigm_(f_) * c1_ + sigm_(i_) * tanh_(q_);
            c1_ = cc;
            float hv = sigm_(o_) * tanh_(cc);
            h1w[(size_t)(tl * 32 + erow) * H_ + ct * 16 + ecol] = (_Float16)hv;
            float ps = hv * fcv;
            ps += __shfl_xor(ps, 1); ps += __shfl_xor(ps, 2);
            ps += __shfl_xor(ps, 4); ps += __shfl_xor(ps, 8);
            if ((tid & 15) == 0) partg[erow * 32 + ct] = ps;
        }
        GBAR();   // barrier B: h1_new + partials visible tile-wide
    }

    // epilogue: final x -> outp column T_-1
    if (ct == 0) {
        floatx2 pv = load8_sc0(partg + erow * 32 + (tid & 15) * 2);
        asm volatile("s_waitcnt vmcnt(0)" : "+v"(pv) :: "memory");
        float xs = pv[0] + pv[1];
        xs += __shfl_xor(xs, 1); xs += __shfl_xor(xs, 2);
        xs += __shfl_xor(xs, 4); xs += __shfl_xor(xs, 8);
        xs += fcb0;
        if ((tid & 15) == 0)
            outp[(size_t)(tl * 32 + erow) * T_ + (T_ - 1)] = xs;
    }
#undef PASS
#undef GBAR
}

extern "C" void kernel_launch(void* const* d_in, const int* in_sizes, int n_in,
                              void* d_out, int out_size, void* d_ws, size_t ws_size,
                              hipStream_t stream) {
    const float* h_in = (const float*)d_in[0];
    const float* c_in = (const float*)d_in[1];
    const float* wih0 = (const float*)d_in[2];
    const float* whh0 = (const float*)d_in[3];
    const float* bih0 = (const float*)d_in[4];
    const float* bhh0 = (const float*)d_in[5];
    const float* wih1 = (const float*)d_in[6];
    const float* whh1 = (const float*)d_in[7];
    const float* bih1 = (const float*)d_in[8];
    const float* bhh1 = (const float*)d_in[9];
    const float* fcw  = (const float*)d_in[10];
    const float* fcb  = (const float*)d_in[11];
    float* out = (float*)d_out;

    char* ws = (char*)d_ws;
    _Float16* w16 = (_Float16*)ws;
    _Float16* Hs0 = (_Float16*)(ws + H0_OFF);
    _Float16* Hs1 = (_Float16*)(ws + H1_OFF);
    int* bar      = (int*)(ws + BAR_OFF);
    float* part   = (float*)(ws + PART_OFF);

    // flags + rank counters must start at 0 (ws poisoned between calls)
    (void)hipMemsetAsync(bar, 0, 8192, stream);

    {
        const int n4 = 3 * (4 * H_ * H_) / 4;
        prep_weights<<<(n4 + 255) / 256, 256, 0, stream>>>(whh0, wih1, whh1, w16);
    }
    prep_state<<<(B_ * H_ / 4) / 256, 256, 0, stream>>>(h_in, Hs0, Hs1);

    lstm_decode<<<NWG, NTHR, 0, stream>>>(c_in, wih0, bih0, bhh0, bih1, bhh1,
                                          fcw, fcb, w16, Hs0, Hs1, bar, part, out);
}

// Round 12
// 1814.750 us; speedup vs baseline: 2.6172x; 2.6172x over previous
//
#include <hip/hip_runtime.h>
#include <hip/hip_bf16.h>

// MomentumDecoder: 2-layer LSTM (B=512,H=512), 256 autoregressive steps.
// Round 12: r6 base (best: 2.42ms) + split-phase barriers.
// Signal each flag EARLY, run independent local MFMA (PASS2 after signal A,
// PASS0(t+1) after signal B), poll LATE -> the flag round-trip latency is
// hidden under compute instead of exposed. 256 WGs x 512 thr (1/CU),
// XCD-local groups, weights fully VGPR-resident (96), L2 data path.

#define B_ 512
#define H_ 512
#define T_ 256
#define NWG 256
#define NTHR 512

typedef _Float16 half8_t __attribute__((ext_vector_type(8)));
typedef _Float16 half4_t __attribute__((ext_vector_type(4)));
typedef _Float16 half2_t __attribute__((ext_vector_type(2)));
typedef float floatx4 __attribute__((ext_vector_type(4)));

// ---- d_ws layout ----
#define W16_BYTES  (3u * 4u * H_ * H_ * 2u)     // 6 MiB f16 [W_hh0|W_ih1|W_hh1]
#define HBUF_ELEMS (B_ * H_)
#define HBUF_BYTES (HBUF_ELEMS * 2u)
#define H0_OFF   ((size_t)W16_BYTES)
#define H1_OFF   (H0_OFF + 2 * HBUF_BYTES)
#define BAR_OFF  (H1_OFF + 2 * HBUF_BYTES)      // 256 flag ints + 8 rank ints
#define PART_OFF (BAR_OFF + 2048)

__device__ __forceinline__ float sigm_(float x) { return 1.0f / (1.0f + __expf(-x)); }
__device__ __forceinline__ float tanh_(float x) { return 1.0f - 2.0f / (1.0f + __expf(2.0f * x)); }

// ---------------- prep kernels (r6-proven) ----------------
__global__ void prep_weights(const float* __restrict__ whh0,
                             const float* __restrict__ wih1,
                             const float* __restrict__ whh1,
                             _Float16* __restrict__ w16) {
    const int QM = (4 * H_ * H_) / 4;
    int i = blockIdx.x * blockDim.x + threadIdx.x;
    if (i >= 3 * QM) return;
    const float* src; int base;
    if (i < QM)          { src = whh0; base = 0; }
    else if (i < 2 * QM) { src = wih1; base = QM; }
    else                 { src = whh1; base = 2 * QM; }
    float4 v = ((const float4*)src)[i - base];
    half4_t h;
    h[0] = (_Float16)v.x; h[1] = (_Float16)v.y; h[2] = (_Float16)v.z; h[3] = (_Float16)v.w;
    ((half4_t*)w16)[i] = h;
}

__global__ void prep_state(const float* __restrict__ h_in,
                           _Float16* __restrict__ H0, _Float16* __restrict__ H1) {
    int i = blockIdx.x * blockDim.x + threadIdx.x;
    float4 a = ((const float4*)h_in)[i];
    float4 b = ((const float4*)h_in)[(B_ * H_) / 4 + i];
    half4_t ha, hb;
    ha[0] = (_Float16)a.x; ha[1] = (_Float16)a.y; ha[2] = (_Float16)a.z; ha[3] = (_Float16)a.w;
    hb[0] = (_Float16)b.x; hb[1] = (_Float16)b.y; hb[2] = (_Float16)b.z; hb[3] = (_Float16)b.w;
    ((half4_t*)H0)[i] = ha;
    ((half4_t*)H1)[i] = hb;
}

// ---------------- helpers ----------------
// global->LDS 16B, aux=0x01 (SC0: L1 bypass; served from the XCD's L2)
#define GLL16(gptr, lptr) __builtin_amdgcn_global_load_lds( \
    (const __attribute__((address_space(1))) unsigned int*)(gptr), \
    (__attribute__((address_space(3))) unsigned int*)(lptr), 16, 0, 0x01)

// Stage this wave's 8 rows of a 64x512 f16 tile (pre-swizzled source).
__device__ __forceinline__ void stage_rows(const char* gsrc, char* lbuf, int wv, int lane) {
#pragma unroll
    for (int i = 0; i < 8; ++i) {
        int row = wv * 8 + i;
        const char* g_ = gsrc + row * 1024 + (((lane ^ (row & 7)) & 63) << 4);
        GLL16(g_, lbuf + row * 1024);
    }
}

// sc0 16B load (L1 bypass, L2-served)
__device__ __forceinline__ floatx4 load16_sc0(const float* p) {
    floatx4 v;
    asm volatile("global_load_dwordx4 %0, %1, off sc0" : "=v"(v) : "v"(p) : "memory");
    return v;
}

// ---------------- main persistent kernel ----------------
__launch_bounds__(NTHR)
__global__ void lstm_decode(
    const float* __restrict__ c_in,
    const float* __restrict__ wih0, const float* __restrict__ bih0,
    const float* __restrict__ bhh0,
    const float* __restrict__ bih1, const float* __restrict__ bhh1,
    const float* __restrict__ fcw, const float* __restrict__ fcb,
    const _Float16* __restrict__ w16,
    _Float16* __restrict__ Hs0, _Float16* __restrict__ Hs1,
    int* __restrict__ bar, float* __restrict__ part,
    float* __restrict__ outp)
{
    __shared__ __align__(16) char bufA[65536];   // h1 tile
    __shared__ __align__(16) char bufB[65536];   // h0 tile
    __shared__ float gbuf[4][64][20];            // gate exchange, padded
    __shared__ float xrow[64];
    __shared__ int sh_bt, sh_ct;

    const int tid  = (int)threadIdx.x;
    const int lane = tid & 63;
    const int wv   = tid >> 6;    // 0..7
    const int g    = wv & 3;      // gate (i,f,g,o)
    const int kh   = wv >> 2;     // K half
    const int cl   = lane & 15;
    const int kg   = lane >> 4;   // 0..3

    // ---- XCD-local group formation (r6-proven) ----
    if (tid == 0) {
        unsigned int xcc;
        asm volatile("s_getreg_b32 %0, hwreg(HW_REG_XCC_ID)" : "=s"(xcc));
        int mybt = (int)(xcc & 7u);
        int rank = atomicAdd(&bar[256 + mybt], 1);   // agent-scope
        sh_bt = mybt;
        sh_ct = rank & 31;
    }
    __syncthreads();
    const int bt = sh_bt;
    const int ct = sh_ct;

    // ---- persistent weight fragments (96 VGPRs) ----
    const int n = g * H_ + ct * 16 + cl;
    half8_t wf0[8], wf1[8], wf2[8];
    {
        const _Float16* r0 = w16 + (size_t)n * H_ + kh * 256 + kg * 8;
        const _Float16* r1 = r0 + 4 * H_ * H_;
        const _Float16* r2 = r0 + 8 * H_ * H_;
#pragma unroll
        for (int ksg = 0; ksg < 8; ++ksg) {
            wf0[ksg] = *(const half8_t*)(r0 + ksg * 32);
            wf1[ksg] = *(const half8_t*)(r1 + ksg * 32);
            wf2[ksg] = *(const half8_t*)(r2 + ksg * 32);
        }
    }
    const float b0   = bih0[n] + bhh0[n];
    const float b1   = bih1[n] + bhh1[n];
    const float wx   = wih0[n];
    const float fcb0 = fcb[0];

    // ---- elementwise domain ----
    const int erow = tid >> 3;          // 0..63
    const int ecol = (tid & 7) * 2;     // 0..14 even
    float c0a, c0b, c1a, c1b;
    {
        size_t base0 = (size_t)(bt * 64 + erow) * H_ + ct * 16 + ecol;
        c0a = c_in[base0];                     c0b = c_in[base0 + 1];
        c1a = c_in[(size_t)B_ * H_ + base0];   c1b = c_in[(size_t)B_ * H_ + base0 + 1];
    }
    const float2 fcv = *(const float2*)(fcw + ct * 16 + ecol);

    const int abase = cl * 1024 + kh * 512 + kg * 16;
    const int axor  = (cl & 7) << 4;

    int* flagg   = bar + bt * 32;
    float* partg = part + bt * 2048;   // [64 rows][32 ct]
    int ep = 0;

#define PASS(bufc, wf, acc) do {                                              \
    _Pragma("unroll")                                                         \
    for (int ksg = 0; ksg < 8; ++ksg) {                                       \
        _Pragma("unroll")                                                     \
        for (int mt = 0; mt < 4; ++mt) {                                      \
            int a_ = (abase + mt * 16384 + ksg * 64) ^ axor;                  \
            half8_t av_ = *(const half8_t*)((bufc) + a_);                     \
            acc[mt] = __builtin_amdgcn_mfma_f32_16x16x32_f16(av_, (wf)[ksg],  \
                                                             acc[mt], 0, 0, 0); \
        }                                                                     \
    }                                                                         \
} while (0)

    floatx4 accG0[4], accG1[4];
    floatx4 pv;   // loop-carried FC-partial load

    // ---- prologue: stage h0(0)+h1(0), PASS0 for t=0 ----
    if (tid < 64) xrow[tid] = 0.f;
    stage_rows((const char*)Hs0 + (size_t)bt * 64 * 1024, bufB, wv, lane);
    stage_rows((const char*)Hs1 + (size_t)bt * 64 * 1024, bufA, wv, lane);
    asm volatile("s_waitcnt vmcnt(0) lgkmcnt(0)\n\ts_barrier" ::: "memory");
#pragma unroll
    for (int mt = 0; mt < 4; ++mt) accG0[mt] = (floatx4)0.f;
    PASS(bufB, wf0, accG0);            // G0(0) partial: h0 x W_hh0^T

    for (int t = 0; t < T_; ++t) {
        const size_t pnxt = (size_t)((t + 1) & 1);
        _Float16* h0w = Hs0 + pnxt * HBUF_ELEMS;
        _Float16* h1w = Hs1 + pnxt * HBUF_ELEMS;

        // ---- 1. x-reduce (pv loaded at end of prev iter, 8 GLLs younger) ----
        if (t > 0) {
            asm volatile("s_waitcnt vmcnt(8)" : "+v"(pv) :: "memory");
            float xs = (pv[0] + pv[1]) + (pv[2] + pv[3]);
            xs += __shfl_xor(xs, 1);
            xs += __shfl_xor(xs, 2);
            xs += __shfl_xor(xs, 4);
            xs += fcb0;
            if ((tid & 7) == 0) {
                xrow[tid >> 3] = xs;
                if (ct == 0) outp[(size_t)(bt * 64 + (tid >> 3)) * T_ + (t - 1)] = xs;
            }
        }
        __syncthreads();   // xrow visible; drains bufA staging from prev iter

        // ---- 2. exchange G0 (kh0 write injects bias + x; kh1 adds) ----
        if (kh == 0) {
#pragma unroll
            for (int mt = 0; mt < 4; ++mt)
#pragma unroll
                for (int r = 0; r < 4; ++r)
                    gbuf[g][mt * 16 + kg * 4 + r][cl] =
                        accG0[mt][r] + __builtin_fmaf(xrow[mt * 16 + kg * 4 + r], wx, b0);
        }
        __syncthreads();
        if (kh == 1) {
#pragma unroll
            for (int mt = 0; mt < 4; ++mt)
#pragma unroll
                for (int r = 0; r < 4; ++r)
                    gbuf[g][mt * 16 + kg * 4 + r][cl] += accG0[mt][r];
        }
        __syncthreads();

        // ---- 3. EW layer 0 ----
        {
            float2 iv = *(const float2*)&gbuf[0][erow][ecol];
            float2 fv = *(const float2*)&gbuf[1][erow][ecol];
            float2 gv = *(const float2*)&gbuf[2][erow][ecol];
            float2 ov = *(const float2*)&gbuf[3][erow][ecol];
            float ca = sigm_(fv.x) * c0a + sigm_(iv.x) * tanh_(gv.x);
            float cb = sigm_(fv.y) * c0b + sigm_(iv.y) * tanh_(gv.y);
            c0a = ca; c0b = cb;
            half2_t hh;
            hh[0] = (_Float16)(sigm_(ov.x) * tanh_(ca));
            hh[1] = (_Float16)(sigm_(ov.y) * tanh_(cb));
            *(half2_t*)(h0w + (size_t)(bt * 64 + erow) * H_ + ct * 16 + ecol) = hh;
        }

        // ---- 4. SIGNAL A (early) ----
        ++ep;
        __syncthreads();   // drains h0_new stores to L2
        if (tid == 0)
            __hip_atomic_store(&flagg[ct], ep, __ATOMIC_RELAXED, __HIP_MEMORY_SCOPE_AGENT);

        // ---- 5. PASS2: G1 = bias + h1(bufA) x W_hh1^T  (independent) ----
#pragma unroll
        for (int mt = 0; mt < 4; ++mt) {
            if (kh == 0) {
#pragma unroll
                for (int r = 0; r < 4; ++r) accG1[mt][r] = b1;
            } else {
                accG1[mt] = (floatx4)0.f;
            }
        }
        PASS(bufA, wf2, accG1);

        // ---- 6. POLL A (late) ----
        if (wv == 0) {
            for (;;) {
                int v_ = __hip_atomic_load(&flagg[lane & 31], __ATOMIC_RELAXED,
                                           __HIP_MEMORY_SCOPE_AGENT);
                if (__all(v_ >= ep)) break;
            }
        }
        __syncthreads();

        // ---- 7. stage h0_new -> bufB ----
        stage_rows((const char*)h0w + (size_t)bt * 64 * 1024, bufB, wv, lane);
        asm volatile("s_waitcnt vmcnt(0) lgkmcnt(0)\n\ts_barrier" ::: "memory");

        // ---- 8. PASS1: G1 += h0_new x W_ih1^T ----
        PASS(bufB, wf1, accG1);

        // ---- 9. exchange G1 (bias already in kh0 init) ----
        if (kh == 0) {
#pragma unroll
            for (int mt = 0; mt < 4; ++mt)
#pragma unroll
                for (int r = 0; r < 4; ++r)
                    gbuf[g][mt * 16 + kg * 4 + r][cl] = accG1[mt][r];
        }
        __syncthreads();
        if (kh == 1) {
#pragma unroll
            for (int mt = 0; mt < 4; ++mt)
#pragma unroll
                for (int r = 0; r < 4; ++r)
                    gbuf[g][mt * 16 + kg * 4 + r][cl] += accG1[mt][r];
        }
        __syncthreads();

        // ---- 10. EW layer 1 + FC partial ----
        {
            float2 iv = *(const float2*)&gbuf[0][erow][ecol];
            float2 fv = *(const float2*)&gbuf[1][erow][ecol];
            float2 gv = *(const float2*)&gbuf[2][erow][ecol];
            float2 ov = *(const float2*)&gbuf[3][erow][ecol];
            float ca = sigm_(fv.x) * c1a + sigm_(iv.x) * tanh_(gv.x);
            float cb = sigm_(fv.y) * c1b + sigm_(iv.y) * tanh_(gv.y);
            c1a = ca; c1b = cb;
            float ha = sigm_(ov.x) * tanh_(ca);
            float hb = sigm_(ov.y) * tanh_(cb);
            half2_t hh; hh[0] = (_Float16)ha; hh[1] = (_Float16)hb;
            *(half2_t*)(h1w + (size_t)(bt * 64 + erow) * H_ + ct * 16 + ecol) = hh;
            float ps = __builtin_fmaf(ha, fcv.x, hb * fcv.y);
            ps += __shfl_xor(ps, 1);
            ps += __shfl_xor(ps, 2);
            ps += __shfl_xor(ps, 4);
            if ((tid & 7) == 0)
                partg[(tid >> 3) * 32 + ct] = ps;
        }

        // ---- 11. SIGNAL B (early) ----
        ++ep;
        __syncthreads();   // drains h1_new + partial stores
        if (tid == 0)
            __hip_atomic_store(&flagg[ct], ep, __ATOMIC_RELAXED, __HIP_MEMORY_SCOPE_AGENT);

        // ---- 12. PASS0(t+1): G0 = h0_new(bufB) x W_hh0^T (independent) ----
#pragma unroll
        for (int mt = 0; mt < 4; ++mt) accG0[mt] = (floatx4)0.f;
        PASS(bufB, wf0, accG0);

        // ---- 13. POLL B (late) ----
        if (wv == 0) {
            for (;;) {
                int v_ = __hip_atomic_load(&flagg[lane & 31], __ATOMIC_RELAXED,
                                           __HIP_MEMORY_SCOPE_AGENT);
                if (__all(v_ >= ep)) break;
            }
        }
        __syncthreads();

        // ---- 14. issue x-partial load + stage h1(t+1) -> bufA ----
        pv = load16_sc0(partg + (tid >> 3) * 32 + (tid & 7) * 4);
        stage_rows((const char*)Hs1 + pnxt * HBUF_BYTES + (size_t)bt * 64 * 1024,
                   bufA, wv, lane);
    }

    // ---- epilogue: final x -> outp column T_-1 ----
    {
        asm volatile("s_waitcnt vmcnt(8)" : "+v"(pv) :: "memory");
        float xs = (pv[0] + pv[1]) + (pv[2] + pv[3]);
        xs += __shfl_xor(xs, 1);
        xs += __shfl_xor(xs, 2);
        xs += __shfl_xor(xs, 4);
        xs += fcb0;
        if ((tid & 7) == 0 && ct == 0)
            outp[(size_t)(bt * 64 + (tid >> 3)) * T_ + (T_ - 1)] = xs;
    }
#undef PASS
}

extern "C" void kernel_launch(void* const* d_in, const int* in_sizes, int n_in,
                              void* d_out, int out_size, void* d_ws, size_t ws_size,
                              hipStream_t stream) {
    const float* h_in = (const float*)d_in[0];
    const float* c_in = (const float*)d_in[1];
    const float* wih0 = (const float*)d_in[2];
    const float* whh0 = (const float*)d_in[3];
    const float* bih0 = (const float*)d_in[4];
    const float* bhh0 = (const float*)d_in[5];
    const float* wih1 = (const float*)d_in[6];
    const float* whh1 = (const float*)d_in[7];
    const float* bih1 = (const float*)d_in[8];
    const float* bhh1 = (const float*)d_in[9];
    const float* fcw  = (const float*)d_in[10];
    const float* fcb  = (const float*)d_in[11];
    float* out = (float*)d_out;

    char* ws = (char*)d_ws;
    _Float16* w16 = (_Float16*)ws;
    _Float16* Hs0 = (_Float16*)(ws + H0_OFF);
    _Float16* Hs1 = (_Float16*)(ws + H1_OFF);
    int* bar      = (int*)(ws + BAR_OFF);
    float* part   = (float*)(ws + PART_OFF);

    // flags + rank counters must start at 0 (ws poisoned between calls)
    (void)hipMemsetAsync(bar, 0, 2048, stream);

    {
        const int n4 = 3 * (4 * H_ * H_) / 4;
        prep_weights<<<(n4 + 255) / 256, 256, 0, stream>>>(whh0, wih1, whh1, w16);
    }
    prep_state<<<(B_ * H_ / 4) / 256, 256, 0, stream>>>(h_in, Hs0, Hs1);

    lstm_decode<<<NWG, NTHR, 0, stream>>>(c_in, wih0, bih0, bhh0, bih1, bhh1,
                                          fcw, fcb, w16, Hs0, Hs1, bar, part, out);
}

// Round 13
// 1806.246 us; speedup vs baseline: 2.6295x; 1.0047x over previous
//
#include <hip/hip_runtime.h>
#include <hip/hip_bf16.h>

// MomentumDecoder: 2-layer LSTM (B=512,H=512), 256 autoregressive steps.
// Round 13: r12 (1.81ms) + latency-hiding micro-schedule:
//  (1) xrow/exchange barriers are lgkmcnt-only (bufA stage stays in flight
//      until step-4's full drain -> hidden under x-reduce/exchange/EW0)
//  (2) PASS2 split around poll A + bufB stage issue (stage latency under mt23)
//  (3) PASS0 split around poll B + bufA stage issue (stage latency under mt23)
// Protocol (flags, scopes, vmcnt(8) pv discipline) identical to r12.

#define B_ 512
#define H_ 512
#define T_ 256
#define NWG 256
#define NTHR 512

typedef _Float16 half8_t __attribute__((ext_vector_type(8)));
typedef _Float16 half4_t __attribute__((ext_vector_type(4)));
typedef _Float16 half2_t __attribute__((ext_vector_type(2)));
typedef float floatx4 __attribute__((ext_vector_type(4)));

// ---- d_ws layout ----
#define W16_BYTES  (3u * 4u * H_ * H_ * 2u)     // 6 MiB f16 [W_hh0|W_ih1|W_hh1]
#define HBUF_ELEMS (B_ * H_)
#define HBUF_BYTES (HBUF_ELEMS * 2u)
#define H0_OFF   ((size_t)W16_BYTES)
#define H1_OFF   (H0_OFF + 2 * HBUF_BYTES)
#define BAR_OFF  (H1_OFF + 2 * HBUF_BYTES)      // 256 flag ints + 8 rank ints
#define PART_OFF (BAR_OFF + 2048)

__device__ __forceinline__ float sigm_(float x) { return 1.0f / (1.0f + __expf(-x)); }
__device__ __forceinline__ float tanh_(float x) { return 1.0f - 2.0f / (1.0f + __expf(2.0f * x)); }

// ---------------- prep kernels (r6-proven) ----------------
__global__ void prep_weights(const float* __restrict__ whh0,
                             const float* __restrict__ wih1,
                             const float* __restrict__ whh1,
                             _Float16* __restrict__ w16) {
    const int QM = (4 * H_ * H_) / 4;
    int i = blockIdx.x * blockDim.x + threadIdx.x;
    if (i >= 3 * QM) return;
    const float* src; int base;
    if (i < QM)          { src = whh0; base = 0; }
    else if (i < 2 * QM) { src = wih1; base = QM; }
    else                 { src = whh1; base = 2 * QM; }
    float4 v = ((const float4*)src)[i - base];
    half4_t h;
    h[0] = (_Float16)v.x; h[1] = (_Float16)v.y; h[2] = (_Float16)v.z; h[3] = (_Float16)v.w;
    ((half4_t*)w16)[i] = h;
}

__global__ void prep_state(const float* __restrict__ h_in,
                           _Float16* __restrict__ H0, _Float16* __restrict__ H1) {
    int i = blockIdx.x * blockDim.x + threadIdx.x;
    float4 a = ((const float4*)h_in)[i];
    float4 b = ((const float4*)h_in)[(B_ * H_) / 4 + i];
    half4_t ha, hb;
    ha[0] = (_Float16)a.x; ha[1] = (_Float16)a.y; ha[2] = (_Float16)a.z; ha[3] = (_Float16)a.w;
    hb[0] = (_Float16)b.x; hb[1] = (_Float16)b.y; hb[2] = (_Float16)b.z; hb[3] = (_Float16)b.w;
    ((half4_t*)H0)[i] = ha;
    ((half4_t*)H1)[i] = hb;
}

// ---------------- helpers ----------------
// global->LDS 16B, aux=0x01 (SC0: L1 bypass; served from the XCD's L2)
#define GLL16(gptr, lptr) __builtin_amdgcn_global_load_lds( \
    (const __attribute__((address_space(1))) unsigned int*)(gptr), \
    (__attribute__((address_space(3))) unsigned int*)(lptr), 16, 0, 0x01)

// Stage this wave's 8 rows of a 64x512 f16 tile (pre-swizzled source).
__device__ __forceinline__ void stage_rows(const char* gsrc, char* lbuf, int wv, int lane) {
#pragma unroll
    for (int i = 0; i < 8; ++i) {
        int row = wv * 8 + i;
        const char* g_ = gsrc + row * 1024 + (((lane ^ (row & 7)) & 63) << 4);
        GLL16(g_, lbuf + row * 1024);
    }
}

// sc0 16B load (L1 bypass, L2-served)
__device__ __forceinline__ floatx4 load16_sc0(const float* p) {
    floatx4 v;
    asm volatile("global_load_dwordx4 %0, %1, off sc0" : "=v"(v) : "v"(p) : "memory");
    return v;
}

// LDS-only barrier: does NOT drain vmcnt (keeps global_load_lds in flight)
#define LBAR() asm volatile("s_waitcnt lgkmcnt(0)\n\ts_barrier" ::: "memory")
// full drain barrier
#define FBAR() asm volatile("s_waitcnt vmcnt(0) lgkmcnt(0)\n\ts_barrier" ::: "memory")

// ---------------- main persistent kernel ----------------
__launch_bounds__(NTHR)
__global__ void lstm_decode(
    const float* __restrict__ c_in,
    const float* __restrict__ wih0, const float* __restrict__ bih0,
    const float* __restrict__ bhh0,
    const float* __restrict__ bih1, const float* __restrict__ bhh1,
    const float* __restrict__ fcw, const float* __restrict__ fcb,
    const _Float16* __restrict__ w16,
    _Float16* __restrict__ Hs0, _Float16* __restrict__ Hs1,
    int* __restrict__ bar, float* __restrict__ part,
    float* __restrict__ outp)
{
    __shared__ __align__(16) char bufA[65536];   // h1 tile
    __shared__ __align__(16) char bufB[65536];   // h0 tile
    __shared__ float gbuf[4][64][20];            // gate exchange, padded
    __shared__ float xrow[64];
    __shared__ int sh_bt, sh_ct;

    const int tid  = (int)threadIdx.x;
    const int lane = tid & 63;
    const int wv   = tid >> 6;    // 0..7
    const int g    = wv & 3;      // gate (i,f,g,o)
    const int kh   = wv >> 2;     // K half
    const int cl   = lane & 15;
    const int kg   = lane >> 4;   // 0..3

    // ---- XCD-local group formation (r6-proven) ----
    if (tid == 0) {
        unsigned int xcc;
        asm volatile("s_getreg_b32 %0, hwreg(HW_REG_XCC_ID)" : "=s"(xcc));
        int mybt = (int)(xcc & 7u);
        int rank = atomicAdd(&bar[256 + mybt], 1);   // agent-scope
        sh_bt = mybt;
        sh_ct = rank & 31;
    }
    __syncthreads();
    const int bt = sh_bt;
    const int ct = sh_ct;

    // ---- persistent weight fragments (96 VGPRs) ----
    const int n = g * H_ + ct * 16 + cl;
    half8_t wf0[8], wf1[8], wf2[8];
    {
        const _Float16* r0 = w16 + (size_t)n * H_ + kh * 256 + kg * 8;
        const _Float16* r1 = r0 + 4 * H_ * H_;
        const _Float16* r2 = r0 + 8 * H_ * H_;
#pragma unroll
        for (int ksg = 0; ksg < 8; ++ksg) {
            wf0[ksg] = *(const half8_t*)(r0 + ksg * 32);
            wf1[ksg] = *(const half8_t*)(r1 + ksg * 32);
            wf2[ksg] = *(const half8_t*)(r2 + ksg * 32);
        }
    }
    const float b0   = bih0[n] + bhh0[n];
    const float b1   = bih1[n] + bhh1[n];
    const float wx   = wih0[n];
    const float fcb0 = fcb[0];

    // ---- elementwise domain ----
    const int erow = tid >> 3;          // 0..63
    const int ecol = (tid & 7) * 2;     // 0..14 even
    float c0a, c0b, c1a, c1b;
    {
        size_t base0 = (size_t)(bt * 64 + erow) * H_ + ct * 16 + ecol;
        c0a = c_in[base0];                     c0b = c_in[base0 + 1];
        c1a = c_in[(size_t)B_ * H_ + base0];   c1b = c_in[(size_t)B_ * H_ + base0 + 1];
    }
    const float2 fcv = *(const float2*)(fcw + ct * 16 + ecol);

    const int abase = cl * 1024 + kh * 512 + kg * 16;
    const int axor  = (cl & 7) << 4;

    int* flagg   = bar + bt * 32;
    float* partg = part + bt * 2048;   // [64 rows][32 ct]
    int ep = 0;

// half-pass over mt in {M0, M1}
#define PASSH(bufc, wf, acc, M0, M1) do {                                     \
    _Pragma("unroll")                                                         \
    for (int ksg = 0; ksg < 8; ++ksg) {                                       \
        _Pragma("unroll")                                                     \
        for (int mt = (M0); mt <= (M1); ++mt) {                               \
            int a_ = (abase + mt * 16384 + ksg * 64) ^ axor;                  \
            half8_t av_ = *(const half8_t*)((bufc) + a_);                     \
            acc[mt] = __builtin_amdgcn_mfma_f32_16x16x32_f16(av_, (wf)[ksg],  \
                                                             acc[mt], 0, 0, 0); \
        }                                                                     \
    }                                                                         \
} while (0)

    floatx4 accG0[4], accG1[4];
    floatx4 pv;   // loop-carried FC-partial load

    // ---- prologue: stage h0(0)+h1(0), PASS0 for t=0 ----
    if (tid < 64) xrow[tid] = 0.f;
    stage_rows((const char*)Hs0 + (size_t)bt * 64 * 1024, bufB, wv, lane);
    stage_rows((const char*)Hs1 + (size_t)bt * 64 * 1024, bufA, wv, lane);
    FBAR();
#pragma unroll
    for (int mt = 0; mt < 4; ++mt) accG0[mt] = (floatx4)0.f;
    PASSH(bufB, wf0, accG0, 0, 3);     // G0(0) partial: h0 x W_hh0^T

    for (int t = 0; t < T_; ++t) {
        const size_t pnxt = (size_t)((t + 1) & 1);
        _Float16* h0w = Hs0 + pnxt * HBUF_ELEMS;
        _Float16* h1w = Hs1 + pnxt * HBUF_ELEMS;

        // ---- 1. x-reduce (pv loaded last iter; 8 bufA GLLs younger) ----
        if (t > 0) {
            asm volatile("s_waitcnt vmcnt(8)" : "+v"(pv) :: "memory");
            float xs = (pv[0] + pv[1]) + (pv[2] + pv[3]);
            xs += __shfl_xor(xs, 1);
            xs += __shfl_xor(xs, 2);
            xs += __shfl_xor(xs, 4);
            xs += fcb0;
            if ((tid & 7) == 0) {
                xrow[tid >> 3] = xs;
                if (ct == 0) outp[(size_t)(bt * 64 + (tid >> 3)) * T_ + (t - 1)] = xs;
            }
        }
        LBAR();   // xrow visible; bufA stage GLLs stay in flight

        // ---- 2. exchange G0 (LDS-only barriers) ----
        if (kh == 0) {
#pragma unroll
            for (int mt = 0; mt < 4; ++mt)
#pragma unroll
                for (int r = 0; r < 4; ++r)
                    gbuf[g][mt * 16 + kg * 4 + r][cl] =
                        accG0[mt][r] + __builtin_fmaf(xrow[mt * 16 + kg * 4 + r], wx, b0);
        }
        LBAR();
        if (kh == 1) {
#pragma unroll
            for (int mt = 0; mt < 4; ++mt)
#pragma unroll
                for (int r = 0; r < 4; ++r)
                    gbuf[g][mt * 16 + kg * 4 + r][cl] += accG0[mt][r];
        }
        LBAR();

        // ---- 3. EW layer 0 ----
        {
            float2 iv = *(const float2*)&gbuf[0][erow][ecol];
            float2 fv = *(const float2*)&gbuf[1][erow][ecol];
            float2 gv = *(const float2*)&gbuf[2][erow][ecol];
            float2 ov = *(const float2*)&gbuf[3][erow][ecol];
            float ca = sigm_(fv.x) * c0a + sigm_(iv.x) * tanh_(gv.x);
            float cb = sigm_(fv.y) * c0b + sigm_(iv.y) * tanh_(gv.y);
            c0a = ca; c0b = cb;
            half2_t hh;
            hh[0] = (_Float16)(sigm_(ov.x) * tanh_(ca));
            hh[1] = (_Float16)(sigm_(ov.y) * tanh_(cb));
            *(half2_t*)(h0w + (size_t)(bt * 64 + erow) * H_ + ct * 16 + ecol) = hh;
        }

        // ---- 4. SIGNAL A (full drain: h0_new stores + bufA stage) ----
        ++ep;
        FBAR();
        if (tid == 0)
            __hip_atomic_store(&flagg[ct], ep, __ATOMIC_RELAXED, __HIP_MEMORY_SCOPE_AGENT);

        // ---- 5a. PASS2 first half: G1 = bias + h1 x W_hh1^T (mt 0,1) ----
#pragma unroll
        for (int mt = 0; mt < 4; ++mt) {
            if (kh == 0) {
#pragma unroll
                for (int r = 0; r < 4; ++r) accG1[mt][r] = b1;
            } else {
                accG1[mt] = (floatx4)0.f;
            }
        }
        PASSH(bufA, wf2, accG1, 0, 1);

        // ---- 6. POLL A ----
        if (wv == 0) {
            for (;;) {
                int v_ = __hip_atomic_load(&flagg[lane & 31], __ATOMIC_RELAXED,
                                           __HIP_MEMORY_SCOPE_AGENT);
                if (__all(v_ >= ep)) break;
            }
        }
        __syncthreads();

        // ---- 7a. issue stage h0_new -> bufB ----
        stage_rows((const char*)h0w + (size_t)bt * 64 * 1024, bufB, wv, lane);

        // ---- 5b. PASS2 second half (mt 2,3) covers stage latency ----
        PASSH(bufA, wf2, accG1, 2, 3);

        // ---- 7b. drain stage ----
        FBAR();

        // ---- 8. PASS1: G1 += h0_new x W_ih1^T ----
        PASSH(bufB, wf1, accG1, 0, 3);

        // ---- 9. exchange G1 ----
        if (kh == 0) {
#pragma unroll
            for (int mt = 0; mt < 4; ++mt)
#pragma unroll
                for (int r = 0; r < 4; ++r)
                    gbuf[g][mt * 16 + kg * 4 + r][cl] = accG1[mt][r];
        }
        LBAR();
        if (kh == 1) {
#pragma unroll
            for (int mt = 0; mt < 4; ++mt)
#pragma unroll
                for (int r = 0; r < 4; ++r)
                    gbuf[g][mt * 16 + kg * 4 + r][cl] += accG1[mt][r];
        }
        LBAR();

        // ---- 10. EW layer 1 + FC partial ----
        {
            float2 iv = *(const float2*)&gbuf[0][erow][ecol];
            float2 fv = *(const float2*)&gbuf[1][erow][ecol];
            float2 gv = *(const float2*)&gbuf[2][erow][ecol];
            float2 ov = *(const float2*)&gbuf[3][erow][ecol];
            float ca = sigm_(fv.x) * c1a + sigm_(iv.x) * tanh_(gv.x);
            float cb = sigm_(fv.y) * c1b + sigm_(iv.y) * tanh_(gv.y);
            c1a = ca; c1b = cb;
            float ha = sigm_(ov.x) * tanh_(ca);
            float hb = sigm_(ov.y) * tanh_(cb);
            half2_t hh; hh[0] = (_Float16)ha; hh[1] = (_Float16)hb;
            *(half2_t*)(h1w + (size_t)(bt * 64 + erow) * H_ + ct * 16 + ecol) = hh;
            float ps = __builtin_fmaf(ha, fcv.x, hb * fcv.y);
            ps += __shfl_xor(ps, 1);
            ps += __shfl_xor(ps, 2);
            ps += __shfl_xor(ps, 4);
            if ((tid & 7) == 0)
                partg[(tid >> 3) * 32 + ct] = ps;
        }

        // ---- 11. SIGNAL B (full drain: h1_new + partial stores) ----
        ++ep;
        FBAR();
        if (tid == 0)
            __hip_atomic_store(&flagg[ct], ep, __ATOMIC_RELAXED, __HIP_MEMORY_SCOPE_AGENT);

        // ---- 12a. PASS0(t+1) first half (mt 0,1) ----
#pragma unroll
        for (int mt = 0; mt < 4; ++mt) accG0[mt] = (floatx4)0.f;
        PASSH(bufB, wf0, accG0, 0, 1);

        // ---- 13. POLL B ----
        if (wv == 0) {
            for (;;) {
                int v_ = __hip_atomic_load(&flagg[lane & 31], __ATOMIC_RELAXED,
                                           __HIP_MEMORY_SCOPE_AGENT);
                if (__all(v_ >= ep)) break;
            }
        }
        __syncthreads();

        // ---- 14. issue x-partial load + stage h1(t+1) -> bufA ----
        pv = load16_sc0(partg + (tid >> 3) * 32 + (tid & 7) * 4);
        stage_rows((const char*)Hs1 + pnxt * HBUF_BYTES + (size_t)bt * 64 * 1024,
                   bufA, wv, lane);

        // ---- 12b. PASS0(t+1) second half (mt 2,3) covers stage latency ----
        PASSH(bufB, wf0, accG0, 2, 3);
    }

    // ---- epilogue: final x -> outp column T_-1 ----
    {
        asm volatile("s_waitcnt vmcnt(8)" : "+v"(pv) :: "memory");
        float xs = (pv[0] + pv[1]) + (pv[2] + pv[3]);
        xs += __shfl_xor(xs, 1);
        xs += __shfl_xor(xs, 2);
        xs += __shfl_xor(xs, 4);
        xs += fcb0;
        if ((tid & 7) == 0 && ct == 0)
            outp[(size_t)(bt * 64 + (tid >> 3)) * T_ + (T_ - 1)] = xs;
    }
#undef PASSH
#undef LBAR
#undef FBAR
}

extern "C" void kernel_launch(void* const* d_in, const int* in_sizes, int n_in,
                              void* d_out, int out_size, void* d_ws, size_t ws_size,
                              hipStream_t stream) {
    const float* h_in = (const float*)d_in[0];
    const float* c_in = (const float*)d_in[1];
    const float* wih0 = (const float*)d_in[2];
    const float* whh0 = (const float*)d_in[3];
    const float* bih0 = (const float*)d_in[4];
    const float* bhh0 = (const float*)d_in[5];
    const float* wih1 = (const float*)d_in[6];
    const float* whh1 = (const float*)d_in[7];
    const float* bih1 = (const float*)d_in[8];
    const float* bhh1 = (const float*)d_in[9];
    const float* fcw  = (const float*)d_in[10];
    const float* fcb  = (const float*)d_in[11];
    float* out = (float*)d_out;

    char* ws = (char*)d_ws;
    _Float16* w16 = (_Float16*)ws;
    _Float16* Hs0 = (_Float16*)(ws + H0_OFF);
    _Float16* Hs1 = (_Float16*)(ws + H1_OFF);
    int* bar      = (int*)(ws + BAR_OFF);
    float* part   = (float*)(ws + PART_OFF);

    // flags + rank counters must start at 0 (ws poisoned between calls)
    (void)hipMemsetAsync(bar, 0, 2048, stream);

    {
        const int n4 = 3 * (4 * H_ * H_) / 4;
        prep_weights<<<(n4 + 255) / 256, 256, 0, stream>>>(whh0, wih1, whh1, w16);
    }
    prep_state<<<(B_ * H_ / 4) / 256, 256, 0, stream>>>(h_in, Hs0, Hs1);

    lstm_decode<<<NWG, NTHR, 0, stream>>>(c_in, wih0, bih0, bhh0, bih1, bhh1,
                                          fcw, fcb, w16, Hs0, Hs1, bar, part, out);
}